// Round 1
// baseline (30.444 us; speedup 1.0000x reference)
//
#include <hip/hip_runtime.h>

// Problem constants (from reference setup_inputs): B=8, T=8192, L=4096, D=256.
constexpr int kT = 8192;
constexpr int kL = 4096;
constexpr int kD = 256;          // 256 floats = 64 float4 per row -> one wave per row
constexpr int kRows = 8 * kT;    // B*T total output rows

__global__ __launch_bounds__(256) void Resample_20512763805843_kernel(
    const float* __restrict__ gamma,   // [B*T]
    const float* __restrict__ orig,    // [B*L*D]
    float* __restrict__ out)           // [B*T*D]
{
    // 4 rows per 256-thread block; each 64-lane wave owns one output row.
    const int row  = blockIdx.x * 4 + (threadIdx.x >> 6);
    const int lane = threadIdx.x & 63;
    if (row >= kRows) return;

    const float gs = gamma[row] * (float)(kL - 1);
    int k0 = (int)floorf(gs);
    k0 = k0 < 0 ? 0 : (k0 > kL - 1 ? kL - 1 : k0);
    const int k1 = (k0 + 1 < kL) ? k0 + 1 : kL - 1;
    const float w1 = gs - (float)k0;
    const float w0 = 1.0f - w1;

    const int b = row >> 13;  // row / kT (T = 8192)

    const float4* __restrict__ r0 =
        reinterpret_cast<const float4*>(orig + (((size_t)b * kL + k0) * kD));
    const float4* __restrict__ r1 =
        reinterpret_cast<const float4*>(orig + (((size_t)b * kL + k1) * kD));

    const float4 a = r0[lane];
    const float4 c = r1[lane];

    float4 o;
    o.x = w0 * a.x + w1 * c.x;
    o.y = w0 * a.y + w1 * c.y;
    o.z = w0 * a.z + w1 * c.z;
    o.w = w0 * a.w + w1 * c.w;

    reinterpret_cast<float4*>(out + ((size_t)row * kD))[lane] = o;
}

extern "C" void kernel_launch(void* const* d_in, const int* in_sizes, int n_in,
                              void* d_out, int out_size, void* d_ws, size_t ws_size,
                              hipStream_t stream) {
    const float* gamma = (const float*)d_in[0];   // [B*T] fp32
    const float* orig  = (const float*)d_in[1];   // [B*L*D] fp32
    float* out         = (float*)d_out;           // [B*T*D] fp32

    const int grid = kRows / 4;  // 16384 blocks of 256 threads (4 rows each)
    Resample_20512763805843_kernel<<<grid, 256, 0, stream>>>(gamma, orig, out);
}

// Round 3
// 18.159 us; speedup vs baseline: 1.6766x; 1.6766x over previous
//
#include <hip/hip_runtime.h>

// Problem constants: B=8, T=8192, L=4096, D=256 (fp32 everywhere).
constexpr int kB = 8;
constexpr int kT = 8192;
constexpr int kL = 4096;
constexpr int kD = 256;          // 256 floats = 64 float4 -> one wave covers a row

typedef float f32x4 __attribute__((ext_vector_type(4)));  // clang-native, builtin-friendly

// Each 256-thread block = 4 waves; each wave handles 2 rows -> 8 rows/block.
// blockIdx % 8 selects batch b: with round-robin block->XCD dispatch this pins
// each batch's 4 MiB orig slice to a single XCD's 4 MiB L2.
__global__ __launch_bounds__(256) void Resample_20512763805843_kernel(
    const float* __restrict__ gamma,   // [B*T]
    const float* __restrict__ orig,    // [B*L*D]
    float* __restrict__ out)           // [B*T*D]
{
    const int wave = threadIdx.x >> 6;
    const int lane = threadIdx.x & 63;

    const int b     = blockIdx.x & 7;   // XCD-aligned batch index
    const int local = blockIdx.x >> 3;  // 0..1023
    const int t0    = local * 8 + wave * 2;      // first of 2 rows for this wave

    const int rowA = b * kT + t0;
    const int rowB = rowA + 1;

    const float* __restrict__ ob = orig + (size_t)b * kL * kD;

    // Independent chains for the two rows (ILP for latency hiding).
    const float gsA = gamma[rowA] * (float)(kL - 1);
    const float gsB = gamma[rowB] * (float)(kL - 1);

    int k0A = (int)floorf(gsA);
    k0A = k0A < 0 ? 0 : (k0A > kL - 1 ? kL - 1 : k0A);
    const int k1A = (k0A + 1 < kL) ? k0A + 1 : kL - 1;
    const float w1A = gsA - (float)k0A;
    const float w0A = 1.0f - w1A;

    int k0B = (int)floorf(gsB);
    k0B = k0B < 0 ? 0 : (k0B > kL - 1 ? kL - 1 : k0B);
    const int k1B = (k0B + 1 < kL) ? k0B + 1 : kL - 1;
    const float w1B = gsB - (float)k0B;
    const float w0B = 1.0f - w1B;

    const f32x4 a0 = reinterpret_cast<const f32x4*>(ob + (size_t)k0A * kD)[lane];
    const f32x4 a1 = reinterpret_cast<const f32x4*>(ob + (size_t)k1A * kD)[lane];
    const f32x4 b0 = reinterpret_cast<const f32x4*>(ob + (size_t)k0B * kD)[lane];
    const f32x4 b1 = reinterpret_cast<const f32x4*>(ob + (size_t)k1B * kD)[lane];

    const f32x4 oA = w0A * a0 + w1A * a1;
    const f32x4 oB = w0B * b0 + w1B * b1;

    // Nontemporal: keep the 67 MB output stream from evicting the orig slice in L2.
    __builtin_nontemporal_store(oA, reinterpret_cast<f32x4*>(out + (size_t)rowA * kD) + lane);
    __builtin_nontemporal_store(oB, reinterpret_cast<f32x4*>(out + (size_t)rowB * kD) + lane);
}

extern "C" void kernel_launch(void* const* d_in, const int* in_sizes, int n_in,
                              void* d_out, int out_size, void* d_ws, size_t ws_size,
                              hipStream_t stream) {
    const float* gamma = (const float*)d_in[0];   // [B*T] fp32
    const float* orig  = (const float*)d_in[1];   // [B*L*D] fp32
    float* out         = (float*)d_out;           // [B*T*D] fp32

    const int grid = (kB * kT) / 8;  // 8192 blocks, 8 rows each
    Resample_20512763805843_kernel<<<grid, 256, 0, stream>>>(gamma, orig, out);
}